// Round 2
// baseline (385.008 us; speedup 1.0000x reference)
//
#include <hip/hip_runtime.h>

#define NBATCH 4
#define NN 2048
#define NR 8192            // NBATCH*NN rows
#define TOPK 10

typedef __attribute__((ext_vector_type(4))) float f32x4;
typedef __attribute__((ext_vector_type(8))) short bf16x8;

__device__ inline unsigned short f2bf(float x) {
    unsigned u = __float_as_uint(x);
    unsigned r = (u + 0x7FFF + ((u >> 16) & 1)) >> 16;
    return (unsigned short)r;
}

// ---------------- K1: encoders + fusion + q/k projection (bf16, K=32 padded)
__global__ __launch_bounds__(256) void k1_encode(
    const float* __restrict__ xd, const float* __restrict__ xs,
    const float* __restrict__ Wd, const float* __restrict__ bd,
    const float* __restrict__ Ws, const float* __restrict__ bs,
    const float* __restrict__ Wf, const float* __restrict__ bf,
    const float* __restrict__ Wq, const float* __restrict__ Wk,
    unsigned short* __restrict__ qh, unsigned short* __restrict__ kh)
{
    int wave = threadIdx.x >> 6;
    int lane = threadIdx.x & 63;
    int r = blockIdx.x * 4 + wave;        // 0..8191

    __shared__ float xm[4][16];
    __shared__ float xst[4][8];
    __shared__ float hc[4][128];
    __shared__ float hh[4][64];

    const float* xdr = xd + (size_t)r * 512;
    float acc = 0.f;
    #pragma unroll
    for (int j = 0; j < 8; ++j) acc += xdr[lane + 64*j];
    acc += __shfl_xor(acc, 16);
    acc += __shfl_xor(acc, 32);
    if (lane < 16) xm[wave][lane] = acc * (1.0f/32.0f);
    if (lane < 8)  xst[wave][lane] = xs[(size_t)r*8 + lane];
    __syncthreads();

    float a1 = bd[lane];
    #pragma unroll
    for (int d = 0; d < 16; ++d) a1 += xm[wave][d] * Wd[d*64 + lane];
    a1 = fmaxf(a1, 0.f);
    float a2 = bs[lane];
    #pragma unroll
    for (int d = 0; d < 8; ++d) a2 += xst[wave][d] * Ws[d*64 + lane];
    a2 = fmaxf(a2, 0.f);
    hc[wave][lane] = a1;
    hc[wave][64 + lane] = a2;
    __syncthreads();

    // 4 accumulators: break the 128-long fma dependency chain
    float hv0 = bf[lane], hv1 = 0.f, hv2 = 0.f, hv3 = 0.f;
    #pragma unroll
    for (int j = 0; j < 128; j += 4) {
        hv0 += hc[wave][j]   * Wf[(j)*64   + lane];
        hv1 += hc[wave][j+1] * Wf[(j+1)*64 + lane];
        hv2 += hc[wave][j+2] * Wf[(j+2)*64 + lane];
        hv3 += hc[wave][j+3] * Wf[(j+3)*64 + lane];
    }
    hh[wave][lane] = (hv0 + hv1) + (hv2 + hv3);
    __syncthreads();

    float qv0 = 0.f, qv1 = 0.f, kv0 = 0.f, kv1 = 0.f;
    #pragma unroll
    for (int j = 0; j < 64; j += 2) {
        float h0 = hh[wave][j], h1 = hh[wave][j+1];
        qv0 += h0 * Wq[(j)*64   + lane];
        qv1 += h1 * Wq[(j+1)*64 + lane];
        kv0 += h0 * Wk[(j)*64   + lane];
        kv1 += h1 * Wk[(j+1)*64 + lane];
    }
    float qv = qv0 + qv1, kv = kv0 + kv1;
    // lane = head*16 + dim; layout qh[(b*4+h)*2048 + n][32], dims 16..31 = 0
    int b = r >> 11, n = r & 2047;
    int head = lane >> 4, dim = lane & 15;
    size_t base = ((size_t)(b*4 + head) * NN + n) * 32;
    qh[base + dim] = f2bf(qv);
    qh[base + 16 + dim] = 0;
    kh[base + dim] = f2bf(kv);
    kh[base + 16 + dim] = 0;
}

// ---------------- K3: A base = 0.3*prior; L = -A; fold 0.3*rowsum into diag -
// (launched BEFORE k2 so the fused scatter lands on a complete base)
__global__ __launch_bounds__(256) void k3_base(
    const float* __restrict__ prior, float* __restrict__ Lout,
    float* __restrict__ Aout)
{
    int r = blockIdx.x;
    const float4* pr = (const float4*)(prior + (size_t)r * NN);
    float4* Ar = (float4*)(Aout + (size_t)r * NN);
    float4* Lr = (float4*)(Lout + (size_t)r * NN);
    float sum = 0.f;
    for (int i = threadIdx.x; i < NN/4; i += 256) {
        float4 p = pr[i];
        float4 a; a.x = 0.3f*p.x; a.y = 0.3f*p.y; a.z = 0.3f*p.z; a.w = 0.3f*p.w;
        Ar[i] = a;
        float4 lv; lv.x = -a.x; lv.y = -a.y; lv.z = -a.z; lv.w = -a.w;
        Lr[i] = lv;
        sum += a.x + a.y + a.z + a.w;
    }
    #pragma unroll
    for (int o = 32; o > 0; o >>= 1) sum += __shfl_down(sum, o);
    __shared__ float wsum[4];
    if ((threadIdx.x & 63) == 0) wsum[threadIdx.x >> 6] = sum;
    __syncthreads();
    if (threadIdx.x == 0) {
        float tot = wsum[0] + wsum[1] + wsum[2] + wsum[3];
        atomicAdd(&Lout[(size_t)r * NN + (r & 2047)], tot);
    }
}

// ---------------- K2: fused softmax-sum + head-avg values + top-10 + scatter
// No max subtraction: scores ~ N(0,1) (max ~6), exp(s/4) overflows only at
// s>350 -> softmax without max-sub is exact in f32 here. One stats sweep +
// one value sweep (was 3 sweeps across k2A+k2C).
// grid = 4 batches x 128 row-groups; 512 threads = 8 waves, each owning a
// 256-column strip. LDS ~68KB -> 2 blocks/CU -> 4 waves/SIMD.
__global__ __launch_bounds__(512) void k2_fused(
    const unsigned short* __restrict__ qh, const unsigned short* __restrict__ kh,
    float* __restrict__ Lout, float* __restrict__ Aout)
{
    const float C1 = 0.36067376022224085f;   // 0.25 * log2(e)
    int b  = blockIdx.x >> 7;
    int rg = blockIdx.x & 127;
    int tid = threadIdx.x;
    int w = tid >> 6, l = tid & 63;
    int quad = l >> 4, lo = l & 15;

    __shared__ unsigned short vt[16][2048];  // bf16 values, XOR-swizzled cols
    __shared__ float redS[8][4][16];         // [wave][head][row] partial sums
    __shared__ float r4s[4][16];             // [head][row] 0.25/S
    __shared__ unsigned win[16][TOPK];       // packed winner keys per row

    bf16x8 afrag[4];
    #pragma unroll
    for (int h = 0; h < 4; ++h)
        afrag[h] = *(const bf16x8*)(qh + ((size_t)(b*4+h) * NN + rg*16 + lo) * 32 + quad*8);

    // ---- phase 1: S[h][row] = sum_m exp(s/4), single sweep, no max machinery
    float S[4][4];
    #pragma unroll
    for (int h = 0; h < 4; ++h)
        #pragma unroll
        for (int rr = 0; rr < 4; ++rr) S[h][rr] = 0.f;

    for (int t = 0; t < 16; ++t) {
        int m0 = w*256 + t*16;
        #pragma unroll
        for (int h = 0; h < 4; ++h) {
            bf16x8 bfrag = *(const bf16x8*)(kh + ((size_t)(b*4+h) * NN + m0 + lo) * 32 + quad*8);
            f32x4 acc = {0.f,0.f,0.f,0.f};
            acc = __builtin_amdgcn_mfma_f32_16x16x32_bf16(afrag[h], bfrag, acc, 0, 0, 0);
            #pragma unroll
            for (int rr = 0; rr < 4; ++rr)
                S[h][rr] += exp2f(acc[rr] * C1);
        }
    }
    #pragma unroll
    for (int d = 1; d <= 8; d <<= 1)
        #pragma unroll
        for (int h = 0; h < 4; ++h)
            #pragma unroll
            for (int rr = 0; rr < 4; ++rr)
                S[h][rr] += __shfl_xor(S[h][rr], d);
    if (lo == 0) {
        #pragma unroll
        for (int h = 0; h < 4; ++h)
            #pragma unroll
            for (int rr = 0; rr < 4; ++rr)
                redS[w][h][quad*4 + rr] = S[h][rr];
    }
    __syncthreads();
    if (tid < 64) {
        int hh = tid >> 4, row = tid & 15;
        float s = 0.f;
        #pragma unroll
        for (int ww = 0; ww < 8; ++ww) s += redS[ww][hh][row];
        r4s[hh][row] = 0.25f / s;
    }
    __syncthreads();

    float r4[4][4];
    #pragma unroll
    for (int h = 0; h < 4; ++h)
        #pragma unroll
        for (int rr = 0; rr < 4; ++rr)
            r4[h][rr] = r4s[h][quad*4 + rr];

    // ---- phase 2: combined values -> vt (bf16, swizzled)
    int swz_w = quad << 4;                   // write swizzle = (row>>2)*16
    for (int t = 0; t < 16; ++t) {
        int m0 = w*256 + t*16;
        float vacc[4] = {0.f,0.f,0.f,0.f};
        #pragma unroll
        for (int h = 0; h < 4; ++h) {
            bf16x8 bfrag = *(const bf16x8*)(kh + ((size_t)(b*4+h) * NN + m0 + lo) * 32 + quad*8);
            f32x4 acc = {0.f,0.f,0.f,0.f};
            acc = __builtin_amdgcn_mfma_f32_16x16x32_bf16(afrag[h], bfrag, acc, 0, 0, 0);
            #pragma unroll
            for (int rr = 0; rr < 4; ++rr) {
                float e = exp2f(acc[rr] * C1);
                vacc[rr] = fmaf(e, r4[h][rr], vacc[rr]);
            }
        }
        #pragma unroll
        for (int rr = 0; rr < 4; ++rr)
            vt[quad*4 + rr][(m0 + lo) ^ swz_w] = f2bf(vacc[rr]);
    }
    __syncthreads();

    // ---- phase 3: top-10 per row; wave w handles rows 2w, 2w+1
    // keys packed in u32: (bf16_value << 16) | (2047 - col)  [lossless order]
    for (int rr = 0; rr < 2; ++rr) {
        int row = w*2 + rr;
        int swz = (row >> 2) << 4;
        unsigned tk[TOPK];
        #pragma unroll
        for (int s = 0; s < TOPK; ++s) tk[s] = 0u;
        for (int j = 0; j < 16; ++j) {
            int m1 = 2*l + 128*j;
            unsigned pair = *(const unsigned*)&vt[row][m1 ^ swz];
            unsigned key0 = (pair << 16)          | (unsigned)(2047 - m1);
            unsigned key1 = (pair & 0xFFFF0000u)  | (unsigned)(2046 - m1);
            if (key0 > tk[TOPK-1]) {
                unsigned ck = key0;
                #pragma unroll
                for (int s = 0; s < TOPK; ++s) {
                    bool ins = ck > tk[s];
                    unsigned o = tk[s];
                    tk[s] = ins ? ck : o;
                    ck    = ins ? o  : ck;
                }
            }
            if (key1 > tk[TOPK-1]) {
                unsigned ck = key1;
                #pragma unroll
                for (int s = 0; s < TOPK; ++s) {
                    bool ins = ck > tk[s];
                    unsigned o = tk[s];
                    tk[s] = ins ? ck : o;
                    ck    = ins ? o  : ck;
                }
            }
        }
        // 10 rounds of 64-lane argmax on packed u32 keys (idx makes them unique)
        #pragma unroll 1
        for (int s = 0; s < TOPK; ++s) {
            unsigned kmax = tk[0];
            #pragma unroll
            for (int d = 1; d < 64; d <<= 1) {
                unsigned o = __shfl_xor(kmax, d);
                kmax = (o > kmax) ? o : kmax;
            }
            if (tk[0] == kmax) {   // exactly one winner pops its head
                #pragma unroll
                for (int q = 0; q < TOPK-1; ++q) tk[q] = tk[q+1];
                tk[TOPK-1] = 0u;
            }
            if (l == 0) win[row][s] = kmax;
        }
    }
    __syncthreads();

    // ---- phase 4: symmetric scatter + degree->diagonal, straight from LDS
    if (tid < 16*TOPK) {
        int row = tid / TOPK, s = tid % TOPK;
        unsigned key = win[row][s];
        float wv = 0.35f * __uint_as_float(key & 0xFFFF0000u);  // 0.7*0.5*val
        int j = 2047 - (int)(key & 0x7FFu);
        int n = rg*16 + row;
        size_t rbase = (size_t)(b*NN + n) * NN;
        size_t jbase = (size_t)(b*NN + j) * NN;
        atomicAdd(&Aout[rbase + j],  wv);
        atomicAdd(&Aout[jbase + n],  wv);
        atomicAdd(&Lout[rbase + j], -wv);
        atomicAdd(&Lout[jbase + n], -wv);
        atomicAdd(&Lout[jbase + j],  wv);   // deg[j] -> diag j
        atomicAdd(&Lout[rbase + n],  wv);   // deg[r] -> diag r
    }
}

extern "C" void kernel_launch(void* const* d_in, const int* in_sizes, int n_in,
                              void* d_out, int out_size, void* d_ws, size_t ws_size,
                              hipStream_t stream)
{
    const float* xd    = (const float*)d_in[0];
    const float* xs    = (const float*)d_in[1];
    const float* prior = (const float*)d_in[2];
    const float* Wd    = (const float*)d_in[3];
    const float* bd    = (const float*)d_in[4];
    const float* Ws    = (const float*)d_in[5];
    const float* bs    = (const float*)d_in[6];
    const float* Wf    = (const float*)d_in[7];
    const float* bf    = (const float*)d_in[8];
    const float* Wq    = (const float*)d_in[9];
    const float* Wk    = (const float*)d_in[10];

    float* Lout = (float*)d_out;
    float* Aout = Lout + (size_t)NR * NN;

    unsigned short* qh = (unsigned short*)d_ws;          // 16*2048*32 bf16 = 2MB
    unsigned short* kh = qh + (size_t)16 * NN * 32;      // 2MB

    k1_encode<<<NR/4, 256, 0, stream>>>(xd, xs, Wd, bd, Ws, bs, Wf, bf, Wq, Wk, qh, kh);
    k3_base<<<NR, 256, 0, stream>>>(prior, Lout, Aout);
    k2_fused<<<NBATCH*128, 512, 0, stream>>>(qh, kh, Lout, Aout);
}

// Round 3
// 336.451 us; speedup vs baseline: 1.1443x; 1.1443x over previous
//
#include <hip/hip_runtime.h>

#define NBATCH 4
#define NN 2048
#define NR 8192            // NBATCH*NN rows
#define TOPK 10

typedef __attribute__((ext_vector_type(4))) float f32x4;
typedef __attribute__((ext_vector_type(8))) short bf16x8;

__device__ inline unsigned short f2bf(float x) {
    unsigned u = __float_as_uint(x);
    unsigned r = (u + 0x7FFF + ((u >> 16) & 1)) >> 16;
    return (unsigned short)r;
}

// ---------------- K1: encoders + fusion + q/k projection (bf16, K=32 padded)
__global__ __launch_bounds__(256) void k1_encode(
    const float* __restrict__ xd, const float* __restrict__ xs,
    const float* __restrict__ Wd, const float* __restrict__ bd,
    const float* __restrict__ Ws, const float* __restrict__ bs,
    const float* __restrict__ Wf, const float* __restrict__ bf,
    const float* __restrict__ Wq, const float* __restrict__ Wk,
    unsigned short* __restrict__ qh, unsigned short* __restrict__ kh)
{
    int wave = threadIdx.x >> 6;
    int lane = threadIdx.x & 63;
    int r = blockIdx.x * 4 + wave;        // 0..8191

    __shared__ float xm[4][16];
    __shared__ float xst[4][8];
    __shared__ float hc[4][128];
    __shared__ float hh[4][64];

    const float* xdr = xd + (size_t)r * 512;
    float acc = 0.f;
    #pragma unroll
    for (int j = 0; j < 8; ++j) acc += xdr[lane + 64*j];
    acc += __shfl_xor(acc, 16);
    acc += __shfl_xor(acc, 32);
    if (lane < 16) xm[wave][lane] = acc * (1.0f/32.0f);
    if (lane < 8)  xst[wave][lane] = xs[(size_t)r*8 + lane];
    __syncthreads();

    float a1 = bd[lane];
    #pragma unroll
    for (int d = 0; d < 16; ++d) a1 += xm[wave][d] * Wd[d*64 + lane];
    a1 = fmaxf(a1, 0.f);
    float a2 = bs[lane];
    #pragma unroll
    for (int d = 0; d < 8; ++d) a2 += xst[wave][d] * Ws[d*64 + lane];
    a2 = fmaxf(a2, 0.f);
    hc[wave][lane] = a1;
    hc[wave][64 + lane] = a2;
    __syncthreads();

    // 4 accumulators: break the 128-long fma dependency chain
    float hv0 = bf[lane], hv1 = 0.f, hv2 = 0.f, hv3 = 0.f;
    #pragma unroll
    for (int j = 0; j < 128; j += 4) {
        hv0 += hc[wave][j]   * Wf[(j)*64   + lane];
        hv1 += hc[wave][j+1] * Wf[(j+1)*64 + lane];
        hv2 += hc[wave][j+2] * Wf[(j+2)*64 + lane];
        hv3 += hc[wave][j+3] * Wf[(j+3)*64 + lane];
    }
    hh[wave][lane] = (hv0 + hv1) + (hv2 + hv3);
    __syncthreads();

    float qv0 = 0.f, qv1 = 0.f, kv0 = 0.f, kv1 = 0.f;
    #pragma unroll
    for (int j = 0; j < 64; j += 2) {
        float h0 = hh[wave][j], h1 = hh[wave][j+1];
        qv0 += h0 * Wq[(j)*64   + lane];
        qv1 += h1 * Wq[(j+1)*64 + lane];
        kv0 += h0 * Wk[(j)*64   + lane];
        kv1 += h1 * Wk[(j+1)*64 + lane];
    }
    float qv = qv0 + qv1, kv = kv0 + kv1;
    // lane = head*16 + dim; layout qh[(b*4+h)*2048 + n][32], dims 16..31 = 0
    int b = r >> 11, n = r & 2047;
    int head = lane >> 4, dim = lane & 15;
    size_t base = ((size_t)(b*4 + head) * NN + n) * 32;
    qh[base + dim] = f2bf(qv);
    qh[base + 16 + dim] = 0;
    kh[base + dim] = f2bf(kv);
    kh[base + 16 + dim] = 0;
}

// ---------------- K2A: softmax denominators, single sweep, no max machinery -
// scores ~ N(0,1) (max ~6); exp2(s*0.25*log2e) overflows only at s>350 ->
// no-max softmax exact in f32 here (verified passing in prior round).
// 2048 blocks x 256 thr, ~no LDS -> ~8 blocks/CU: full-occupancy sweep.
__global__ __launch_bounds__(256) void k2a_stats(
    const unsigned short* __restrict__ qh, const unsigned short* __restrict__ kh,
    float* __restrict__ Rf)
{
    const float C1 = 0.36067376022224085f;   // 0.25 * log2(e)
    int bh = blockIdx.x >> 7;                // 16 (b,h) pairs
    int rg = blockIdx.x & 127;               // row group of 16
    int w = threadIdx.x >> 6, l = threadIdx.x & 63;
    int quad = l >> 4, lo = l & 15;

    bf16x8 afrag = *(const bf16x8*)(qh + ((size_t)bh * NN + rg*16 + lo) * 32 + quad*8);
    const unsigned short* kbase = kh + (size_t)bh * NN * 32;

    __shared__ float redA[4][16];

    float Sloc[4] = {0.f,0.f,0.f,0.f};
    for (int t = 0; t < 32; ++t) {
        int m0 = w*512 + t*16;
        bf16x8 bfrag = *(const bf16x8*)(kbase + (size_t)(m0 + lo) * 32 + quad*8);
        f32x4 acc = {0.f,0.f,0.f,0.f};
        acc = __builtin_amdgcn_mfma_f32_16x16x32_bf16(afrag, bfrag, acc, 0, 0, 0);
        #pragma unroll
        for (int rr = 0; rr < 4; ++rr) Sloc[rr] += exp2f(acc[rr] * C1);
    }
    #pragma unroll
    for (int d = 1; d <= 8; d <<= 1) {
        #pragma unroll
        for (int rr = 0; rr < 4; ++rr) Sloc[rr] += __shfl_xor(Sloc[rr], d);
    }
    if (lo == 0) {
        #pragma unroll
        for (int rr = 0; rr < 4; ++rr) redA[w][quad*4 + rr] = Sloc[rr];
    }
    __syncthreads();
    if (threadIdx.x < 16) {
        float S = redA[0][threadIdx.x] + redA[1][threadIdx.x]
                + redA[2][threadIdx.x] + redA[3][threadIdx.x];
        Rf[(size_t)bh * NN + rg*16 + threadIdx.x] = 1.0f / S;
    }
}

// ---------------- K3: A base = 0.3*prior; L = -A; fold 0.3*rowsum into diag -
// (launched BEFORE k2b so the fused scatter lands on a complete base)
__global__ __launch_bounds__(256) void k3_base(
    const float* __restrict__ prior, float* __restrict__ Lout,
    float* __restrict__ Aout)
{
    int r = blockIdx.x;
    const float4* pr = (const float4*)(prior + (size_t)r * NN);
    float4* Ar = (float4*)(Aout + (size_t)r * NN);
    float4* Lr = (float4*)(Lout + (size_t)r * NN);
    float sum = 0.f;
    for (int i = threadIdx.x; i < NN/4; i += 256) {
        float4 p = pr[i];
        float4 a; a.x = 0.3f*p.x; a.y = 0.3f*p.y; a.z = 0.3f*p.z; a.w = 0.3f*p.w;
        Ar[i] = a;
        float4 lv; lv.x = -a.x; lv.y = -a.y; lv.z = -a.z; lv.w = -a.w;
        Lr[i] = lv;
        sum += a.x + a.y + a.z + a.w;
    }
    #pragma unroll
    for (int o = 32; o > 0; o >>= 1) sum += __shfl_down(sum, o);
    __shared__ float wsum[4];
    if ((threadIdx.x & 63) == 0) wsum[threadIdx.x >> 6] = sum;
    __syncthreads();
    if (threadIdx.x == 0) {
        float tot = wsum[0] + wsum[1] + wsum[2] + wsum[3];
        atomicAdd(&Lout[(size_t)r * NN + (r & 2047)], tot);
    }
}

// ---------------- K2B: head-avg values + top-10 + symmetric scatter ---------
// 1024 threads = 16 waves: phase-2 strip = 128 cols/wave; phase-3 = 1 row per
// wave (halved serial top-k chain vs 2 rows/wave). Winners kept in registers
// (lane s remembers round-s winner) -> no win[] LDS, no extra barrier.
__global__ __launch_bounds__(1024) void k2b_topk(
    const unsigned short* __restrict__ qh, const unsigned short* __restrict__ kh,
    const float* __restrict__ Rf,
    float* __restrict__ Lout, float* __restrict__ Aout)
{
    const float C1 = 0.36067376022224085f;   // 0.25 * log2(e)
    int b  = blockIdx.x >> 7;
    int rg = blockIdx.x & 127;
    int tid = threadIdx.x;
    int w = tid >> 6, l = tid & 63;
    int quad = l >> 4, lo = l & 15;

    __shared__ unsigned short vt[16][2048];  // bf16 values, XOR-swizzled cols

    bf16x8 afrag[4];
    float r4[4][4];
    #pragma unroll
    for (int h = 0; h < 4; ++h) {
        int bh = b*4 + h;
        afrag[h] = *(const bf16x8*)(qh + ((size_t)bh * NN + rg*16 + lo) * 32 + quad*8);
        #pragma unroll
        for (int rr = 0; rr < 4; ++rr)
            r4[h][rr] = Rf[(size_t)bh * NN + rg*16 + quad*4 + rr] * 0.25f;
    }

    // ---- phase 2: combined values -> vt (bf16, swizzled)
    int swz_w = quad << 4;                   // write swizzle = (row>>2)*16
    for (int t = 0; t < 8; ++t) {
        int m0 = w*128 + t*16;
        float vacc[4] = {0.f,0.f,0.f,0.f};
        #pragma unroll
        for (int h = 0; h < 4; ++h) {
            bf16x8 bfrag = *(const bf16x8*)(kh + ((size_t)(b*4+h) * NN + m0 + lo) * 32 + quad*8);
            f32x4 acc = {0.f,0.f,0.f,0.f};
            acc = __builtin_amdgcn_mfma_f32_16x16x32_bf16(afrag[h], bfrag, acc, 0, 0, 0);
            #pragma unroll
            for (int rr = 0; rr < 4; ++rr) {
                float e = exp2f(acc[rr] * C1);
                vacc[rr] = fmaf(e, r4[h][rr], vacc[rr]);
            }
        }
        #pragma unroll
        for (int rr = 0; rr < 4; ++rr)
            vt[quad*4 + rr][(m0 + lo) ^ swz_w] = f2bf(vacc[rr]);
    }
    __syncthreads();

    // ---- phase 3: top-10, one row per wave
    // keys packed in u32: (bf16_value << 16) | (2047 - col)  [lossless order]
    {
        int row = w;
        int swz = (row >> 2) << 4;
        unsigned tk[TOPK];
        #pragma unroll
        for (int s = 0; s < TOPK; ++s) tk[s] = 0u;
        for (int j = 0; j < 16; ++j) {
            int m1 = 2*l + 128*j;
            unsigned pair = *(const unsigned*)&vt[row][m1 ^ swz];
            unsigned key0 = (pair << 16)          | (unsigned)(2047 - m1);
            unsigned key1 = (pair & 0xFFFF0000u)  | (unsigned)(2046 - m1);
            if (key0 > tk[TOPK-1]) {
                unsigned ck = key0;
                #pragma unroll
                for (int s = 0; s < TOPK; ++s) {
                    bool ins = ck > tk[s];
                    unsigned o = tk[s];
                    tk[s] = ins ? ck : o;
                    ck    = ins ? o  : ck;
                }
            }
            if (key1 > tk[TOPK-1]) {
                unsigned ck = key1;
                #pragma unroll
                for (int s = 0; s < TOPK; ++s) {
                    bool ins = ck > tk[s];
                    unsigned o = tk[s];
                    tk[s] = ins ? ck : o;
                    ck    = ins ? o  : ck;
                }
            }
        }
        // 10 rounds of 64-lane argmax; lane s keeps round-s winner in a reg
        unsigned mykey = 0u;
        #pragma unroll 1
        for (int s = 0; s < TOPK; ++s) {
            unsigned kmax = tk[0];
            #pragma unroll
            for (int d = 1; d < 64; d <<= 1) {
                unsigned o = __shfl_xor(kmax, d);
                kmax = (o > kmax) ? o : kmax;
            }
            if (tk[0] == kmax) {   // exactly one winner pops its head
                #pragma unroll
                for (int q = 0; q < TOPK-1; ++q) tk[q] = tk[q+1];
                tk[TOPK-1] = 0u;
            }
            if (l == s) mykey = kmax;
        }

        // ---- phase 4: symmetric scatter + degree->diagonal (lanes 0..9)
        if (l < TOPK) {
            float wv = 0.35f * __uint_as_float(mykey & 0xFFFF0000u);  // .7*.5*v
            int j = 2047 - (int)(mykey & 0x7FFu);
            int n = rg*16 + row;
            size_t rbase = (size_t)(b*NN + n) * NN;
            size_t jbase = (size_t)(b*NN + j) * NN;
            atomicAdd(&Aout[rbase + j],  wv);
            atomicAdd(&Aout[jbase + n],  wv);
            atomicAdd(&Lout[rbase + j], -wv);
            atomicAdd(&Lout[jbase + n], -wv);
            atomicAdd(&Lout[jbase + j],  wv);   // deg[j] -> diag j
            atomicAdd(&Lout[rbase + n],  wv);   // deg[r] -> diag r
        }
    }
}

extern "C" void kernel_launch(void* const* d_in, const int* in_sizes, int n_in,
                              void* d_out, int out_size, void* d_ws, size_t ws_size,
                              hipStream_t stream)
{
    const float* xd    = (const float*)d_in[0];
    const float* xs    = (const float*)d_in[1];
    const float* prior = (const float*)d_in[2];
    const float* Wd    = (const float*)d_in[3];
    const float* bd    = (const float*)d_in[4];
    const float* Ws    = (const float*)d_in[5];
    const float* bs    = (const float*)d_in[6];
    const float* Wf    = (const float*)d_in[7];
    const float* bf    = (const float*)d_in[8];
    const float* Wq    = (const float*)d_in[9];
    const float* Wk    = (const float*)d_in[10];

    float* Lout = (float*)d_out;
    float* Aout = Lout + (size_t)NR * NN;

    unsigned short* qh = (unsigned short*)d_ws;          // 16*2048*32 bf16 = 2MB
    unsigned short* kh = qh + (size_t)16 * NN * 32;      // 2MB
    float* Rf  = (float*)(kh + (size_t)16 * NN * 32);    // 16*2048 f32

    k1_encode<<<NR/4, 256, 0, stream>>>(xd, xs, Wd, bd, Ws, bs, Wf, bf, Wq, Wk, qh, kh);
    k2a_stats<<<16*128, 256, 0, stream>>>(qh, kh, Rf);
    k3_base<<<NR, 256, 0, stream>>>(prior, Lout, Aout);
    k2b_topk<<<NBATCH*128, 1024, 0, stream>>>(qh, kh, Rf, Lout, Aout);
}

// Round 4
// 328.524 us; speedup vs baseline: 1.1719x; 1.0241x over previous
//
#include <hip/hip_runtime.h>

#define NBATCH 4
#define NN 2048
#define NR 8192            // NBATCH*NN rows
#define TOPK 10
#define COLSW 2054         // vt row stride in halfwords = 1027 words (odd -> conflict-free)

typedef __attribute__((ext_vector_type(4))) float f32x4;
typedef __attribute__((ext_vector_type(16))) float f32x16;
typedef __attribute__((ext_vector_type(8))) short bf16x8;

__device__ inline unsigned short f2bf(float x) {
    unsigned u = __float_as_uint(x);
    unsigned r = (u + 0x7FFF + ((u >> 16) & 1)) >> 16;
    return (unsigned short)r;
}

// ---------------- K1: encoders + fusion + q/k projection (bf16, dense 16-dim)
__global__ __launch_bounds__(256) void k1_encode(
    const float* __restrict__ xd, const float* __restrict__ xs,
    const float* __restrict__ Wd, const float* __restrict__ bd,
    const float* __restrict__ Ws, const float* __restrict__ bs,
    const float* __restrict__ Wf, const float* __restrict__ bf,
    const float* __restrict__ Wq, const float* __restrict__ Wk,
    unsigned short* __restrict__ qh, unsigned short* __restrict__ kh)
{
    int wave = threadIdx.x >> 6;
    int lane = threadIdx.x & 63;
    int r = blockIdx.x * 4 + wave;        // 0..8191

    __shared__ float xm[4][16];
    __shared__ float xst[4][8];
    __shared__ float hc[4][128];
    __shared__ float hh[4][64];

    const float* xdr = xd + (size_t)r * 512;
    float acc = 0.f;
    #pragma unroll
    for (int j = 0; j < 8; ++j) acc += xdr[lane + 64*j];
    acc += __shfl_xor(acc, 16);
    acc += __shfl_xor(acc, 32);
    if (lane < 16) xm[wave][lane] = acc * (1.0f/32.0f);
    if (lane < 8)  xst[wave][lane] = xs[(size_t)r*8 + lane];
    __syncthreads();

    float a1 = bd[lane];
    #pragma unroll
    for (int d = 0; d < 16; ++d) a1 += xm[wave][d] * Wd[d*64 + lane];
    a1 = fmaxf(a1, 0.f);
    float a2 = bs[lane];
    #pragma unroll
    for (int d = 0; d < 8; ++d) a2 += xst[wave][d] * Ws[d*64 + lane];
    a2 = fmaxf(a2, 0.f);
    hc[wave][lane] = a1;
    hc[wave][64 + lane] = a2;
    __syncthreads();

    // 4 accumulators: break the 128-long fma dependency chain
    float hv0 = bf[lane], hv1 = 0.f, hv2 = 0.f, hv3 = 0.f;
    #pragma unroll
    for (int j = 0; j < 128; j += 4) {
        hv0 += hc[wave][j]   * Wf[(j)*64   + lane];
        hv1 += hc[wave][j+1] * Wf[(j+1)*64 + lane];
        hv2 += hc[wave][j+2] * Wf[(j+2)*64 + lane];
        hv3 += hc[wave][j+3] * Wf[(j+3)*64 + lane];
    }
    hh[wave][lane] = (hv0 + hv1) + (hv2 + hv3);
    __syncthreads();

    float qv0 = 0.f, qv1 = 0.f, kv0 = 0.f, kv1 = 0.f;
    #pragma unroll
    for (int j = 0; j < 64; j += 2) {
        float h0 = hh[wave][j], h1 = hh[wave][j+1];
        qv0 += h0 * Wq[(j)*64   + lane];
        qv1 += h1 * Wq[(j+1)*64 + lane];
        kv0 += h0 * Wk[(j)*64   + lane];
        kv1 += h1 * Wk[(j+1)*64 + lane];
    }
    float qv = qv0 + qv1, kv = kv0 + kv1;
    // lane = head*16 + dim; dense layout qh[(b*4+h)*2048 + n][16]
    int b = r >> 11, n = r & 2047;
    int head = lane >> 4, dim = lane & 15;
    size_t base = ((size_t)(b*4 + head) * NN + n) * 16;
    qh[base + dim] = f2bf(qv);
    kh[base + dim] = f2bf(kv);
}

// ---------------- K2A: softmax denominators via 32x32x16 MFMA (K=16, dense) -
// Swapped operands: A = K-tile (score-col in M), B = Q-tile (q-row in N).
// C/D: n(q-row) = lane&31 -> per-lane softmax sum is a SCALAR.
// scores ~ N(0,1); exp2(s*0.25*log2e) cannot overflow -> no max machinery
// (validated passing in prior rounds).
__global__ __launch_bounds__(256) void k2a_stats(
    const unsigned short* __restrict__ qh, const unsigned short* __restrict__ kh,
    float* __restrict__ Rf)
{
    const float C1 = 0.36067376022224085f;   // 0.25 * log2(e)
    int bh = blockIdx.x >> 6;                // 16 (b,h) pairs
    int rg = blockIdx.x & 63;                // row group of 32
    int w = threadIdx.x >> 6, l = threadIdx.x & 63;
    int row = l & 31, khalf = l >> 5;

    bf16x8 qfrag = *(const bf16x8*)(qh + ((size_t)bh * NN + rg*32 + row) * 16 + khalf*8);
    const unsigned short* kbase = kh + (size_t)bh * NN * 16;

    __shared__ float redS[4][32];

    float Sloc = 0.f;
    for (int t = 0; t < 16; ++t) {           // 512-col strip per wave
        int m0 = w*512 + t*32;
        bf16x8 kfrag = *(const bf16x8*)(kbase + (size_t)(m0 + row) * 16 + khalf*8);
        f32x16 acc = {0.f,0.f,0.f,0.f,0.f,0.f,0.f,0.f,0.f,0.f,0.f,0.f,0.f,0.f,0.f,0.f};
        acc = __builtin_amdgcn_mfma_f32_32x32x16_bf16(kfrag, qfrag, acc, 0, 0, 0);
        #pragma unroll
        for (int rr = 0; rr < 16; ++rr) Sloc += exp2f(acc[rr] * C1);
    }
    Sloc += __shfl_xor(Sloc, 32);            // combine the two khalf col-sets
    if (l < 32) redS[w][l] = Sloc;
    __syncthreads();
    if (threadIdx.x < 32) {
        float S = redS[0][threadIdx.x] + redS[1][threadIdx.x]
                + redS[2][threadIdx.x] + redS[3][threadIdx.x];
        Rf[(size_t)bh * NN + rg*32 + threadIdx.x] = 1.0f / S;
    }
}

// ---------------- K3: A base = 0.3*prior; L = -A; fold 0.3*rowsum into diag -
// (launched BEFORE k2b so the fused scatter lands on a complete base)
__global__ __launch_bounds__(256) void k3_base(
    const float* __restrict__ prior, float* __restrict__ Lout,
    float* __restrict__ Aout)
{
    int r = blockIdx.x;
    const float4* pr = (const float4*)(prior + (size_t)r * NN);
    float4* Ar = (float4*)(Aout + (size_t)r * NN);
    float4* Lr = (float4*)(Lout + (size_t)r * NN);
    float sum = 0.f;
    for (int i = threadIdx.x; i < NN/4; i += 256) {
        float4 p = pr[i];
        float4 a; a.x = 0.3f*p.x; a.y = 0.3f*p.y; a.z = 0.3f*p.z; a.w = 0.3f*p.w;
        Ar[i] = a;
        float4 lv; lv.x = -a.x; lv.y = -a.y; lv.z = -a.z; lv.w = -a.w;
        Lr[i] = lv;
        sum += a.x + a.y + a.z + a.w;
    }
    #pragma unroll
    for (int o = 32; o > 0; o >>= 1) sum += __shfl_down(sum, o);
    __shared__ float wsum[4];
    if ((threadIdx.x & 63) == 0) wsum[threadIdx.x >> 6] = sum;
    __syncthreads();
    if (threadIdx.x == 0) {
        float tot = wsum[0] + wsum[1] + wsum[2] + wsum[3];
        atomicAdd(&Lout[(size_t)r * NN + (r & 2047)], tot);
    }
}

// ---------------- K2B: head-avg values (32x32x16) + top-10 + scatter --------
// 32-row tiles per block; swapped operands put q-row = lane&31, so the
// per-head scale is 4 scalars/lane. vt rows padded to 1027 words (odd) ->
// conflict-free LDS without swizzle. 256 blocks x 1024 thr, 1 block/CU.
__global__ __launch_bounds__(1024, 4) void k2b_topk(
    const unsigned short* __restrict__ qh, const unsigned short* __restrict__ kh,
    const float* __restrict__ Rf,
    float* __restrict__ Lout, float* __restrict__ Aout)
{
    const float C1 = 0.36067376022224085f;   // 0.25 * log2(e)
    int b  = blockIdx.x >> 6;
    int rg = blockIdx.x & 63;                // row group of 32
    int tid = threadIdx.x;
    int w = tid >> 6, l = tid & 63;
    int row = l & 31, khalf = l >> 5;

    __shared__ unsigned short vt[32][COLSW]; // bf16 values, odd-word stride

    bf16x8 qfrag[4];
    float r4[4];
    #pragma unroll
    for (int h = 0; h < 4; ++h) {
        int bh = b*4 + h;
        qfrag[h] = *(const bf16x8*)(qh + ((size_t)bh * NN + rg*32 + row) * 16 + khalf*8);
        r4[h] = Rf[(size_t)bh * NN + rg*32 + row] * 0.25f;
    }

    // ---- phase 2: combined values -> vt; wave strip = 128 cols (4 tiles)
    for (int t = 0; t < 4; ++t) {
        int m0 = w*128 + t*32;
        float vacc[16];
        #pragma unroll
        for (int rr = 0; rr < 16; ++rr) vacc[rr] = 0.f;
        #pragma unroll
        for (int h = 0; h < 4; ++h) {
            bf16x8 kfrag = *(const bf16x8*)(kh + ((size_t)(b*4+h) * NN + m0 + row) * 16 + khalf*8);
            f32x16 acc = {0.f,0.f,0.f,0.f,0.f,0.f,0.f,0.f,0.f,0.f,0.f,0.f,0.f,0.f,0.f,0.f};
            acc = __builtin_amdgcn_mfma_f32_32x32x16_bf16(kfrag, qfrag[h], acc, 0, 0, 0);
            #pragma unroll
            for (int rr = 0; rr < 16; ++rr)
                vacc[rr] = fmaf(exp2f(acc[rr] * C1), r4[h], vacc[rr]);
        }
        // cols: c(reg) = (reg&3) + 8*(reg>>2) + 4*khalf; reg pairs are
        // consecutive even-start cols -> pack 2 bf16 per b32 write
        #pragma unroll
        for (int p = 0; p < 8; ++p) {
            int reg0 = p*2;
            int c = m0 + ((reg0 & 3) + 8*(reg0 >> 2) + 4*khalf);
            unsigned pk = (unsigned)f2bf(vacc[reg0]) | ((unsigned)f2bf(vacc[reg0+1]) << 16);
            *(unsigned*)&vt[row][c] = pk;
        }
    }
    __syncthreads();

    // ---- phase 3: top-10, two rows per wave
    // keys packed in u32: (bf16_value << 16) | (2047 - col)  [lossless order]
    #pragma unroll 1
    for (int rr2 = 0; rr2 < 2; ++rr2) {
        int prow = w*2 + rr2;
        unsigned tk[TOPK];
        #pragma unroll
        for (int s = 0; s < TOPK; ++s) tk[s] = 0u;
        for (int j = 0; j < 16; ++j) {
            int m1 = 2*l + 128*j;
            unsigned pair = *(const unsigned*)&vt[prow][m1];
            unsigned key0 = (pair << 16)          | (unsigned)(2047 - m1);
            unsigned key1 = (pair & 0xFFFF0000u)  | (unsigned)(2046 - m1);
            if (key0 > tk[TOPK-1]) {
                unsigned ck = key0;
                #pragma unroll
                for (int s = 0; s < TOPK; ++s) {
                    bool ins = ck > tk[s];
                    unsigned o = tk[s];
                    tk[s] = ins ? ck : o;
                    ck    = ins ? o  : ck;
                }
            }
            if (key1 > tk[TOPK-1]) {
                unsigned ck = key1;
                #pragma unroll
                for (int s = 0; s < TOPK; ++s) {
                    bool ins = ck > tk[s];
                    unsigned o = tk[s];
                    tk[s] = ins ? ck : o;
                    ck    = ins ? o  : ck;
                }
            }
        }
        // 10 rounds of 64-lane argmax; lane s keeps round-s winner in a reg
        unsigned mykey = 0u;
        #pragma unroll 1
        for (int s = 0; s < TOPK; ++s) {
            unsigned kmax = tk[0];
            #pragma unroll
            for (int d = 1; d < 64; d <<= 1) {
                unsigned o = __shfl_xor(kmax, d);
                kmax = (o > kmax) ? o : kmax;
            }
            if (tk[0] == kmax) {   // exactly one winner pops its head
                #pragma unroll
                for (int q = 0; q < TOPK-1; ++q) tk[q] = tk[q+1];
                tk[TOPK-1] = 0u;
            }
            if (l == s) mykey = kmax;
        }

        // ---- phase 4: symmetric scatter + degree->diagonal (lanes 0..9)
        if (l < TOPK) {
            float wv = 0.35f * __uint_as_float(mykey & 0xFFFF0000u);  // .7*.5*v
            int j = 2047 - (int)(mykey & 0x7FFu);
            int n = rg*32 + prow;
            size_t rbase = (size_t)(b*NN + n) * NN;
            size_t jbase = (size_t)(b*NN + j) * NN;
            atomicAdd(&Aout[rbase + j],  wv);
            atomicAdd(&Aout[jbase + n],  wv);
            atomicAdd(&Lout[rbase + j], -wv);
            atomicAdd(&Lout[jbase + n], -wv);
            atomicAdd(&Lout[jbase + j],  wv);   // deg[j] -> diag j
            atomicAdd(&Lout[rbase + n],  wv);   // deg[r] -> diag r
        }
    }
}

extern "C" void kernel_launch(void* const* d_in, const int* in_sizes, int n_in,
                              void* d_out, int out_size, void* d_ws, size_t ws_size,
                              hipStream_t stream)
{
    const float* xd    = (const float*)d_in[0];
    const float* xs    = (const float*)d_in[1];
    const float* prior = (const float*)d_in[2];
    const float* Wd    = (const float*)d_in[3];
    const float* bd    = (const float*)d_in[4];
    const float* Ws    = (const float*)d_in[5];
    const float* bs    = (const float*)d_in[6];
    const float* Wf    = (const float*)d_in[7];
    const float* bf    = (const float*)d_in[8];
    const float* Wq    = (const float*)d_in[9];
    const float* Wk    = (const float*)d_in[10];

    float* Lout = (float*)d_out;
    float* Aout = Lout + (size_t)NR * NN;

    unsigned short* qh = (unsigned short*)d_ws;          // 16*2048*16 bf16 = 1MB
    unsigned short* kh = qh + (size_t)16 * NN * 16;      // 1MB
    float* Rf  = (float*)(kh + (size_t)16 * NN * 16);    // 16*2048 f32

    k1_encode<<<NR/4, 256, 0, stream>>>(xd, xs, Wd, bd, Ws, bs, Wf, bf, Wq, Wk, qh, kh);
    k2a_stats<<<16*64, 256, 0, stream>>>(qh, kh, Rf);
    k3_base<<<NR, 256, 0, stream>>>(prior, Lout, Aout);
    k2b_topk<<<NBATCH*64, 1024, 0, stream>>>(qh, kh, Rf, Lout, Aout);
}